// Round 3
// baseline (139.586 us; speedup 1.0000x reference)
//
#include <hip/hip_runtime.h>
#include <cstdint>
#include <cstddef>

// Problem constants
#define NB_B 8
#define NL   64
#define NT   512
#define CF   128
#define HD   128
#define NK   10
#define NE   1024

// d_out flat offsets (fp32 elements), reference return order:
// pi[P,10], sigma[P,10], mu[P,10], dist[P,1], atom_types[512,28], bond_types[1024,6], C_batch[P]
static constexpr size_t P_TOT    = (size_t)NB_B * NL * NT;     // 262144
static constexpr size_t PI_OFF   = 0;
static constexpr size_t SIG_OFF  = P_TOT * 10;                  // 2621440
static constexpr size_t MU_OFF   = SIG_OFF + P_TOT * 10;        // 5242880
static constexpr size_t DIST_OFF = MU_OFF + P_TOT * 10;         // 7864320
static constexpr size_t AT_OFF   = DIST_OFF + P_TOT;            // 8126464
static constexpr size_t BD_OFF   = AT_OFF + 512 * 28;           // 8140800
static constexpr size_t CB_OFF   = BD_OFF + NE * 6;             // 8146944

typedef __attribute__((ext_vector_type(8))) short short8;
typedef __attribute__((ext_vector_type(4))) float floatx4;
typedef __attribute__((ext_vector_type(2))) float floatx2;

__device__ __forceinline__ float bf2f(unsigned short u) {
    return __uint_as_float(((unsigned int)u) << 16);
}
__device__ __forceinline__ unsigned short f2bf(float f) {
    unsigned int x = __float_as_uint(f);
    x = (x + 0x7FFFu + ((x >> 16) & 1u)) >> 16;   // RNE
    return (unsigned short)x;
}

// ---------------------------------------------------------------------------
// Kernel 1 (fp32 inputs): precompute folded zl'/zt' rows (bf16 in ws),
// packed head-weight matrix (bf16), atom_types, bond_types (fp32 out).
// zl'[i,h] = (hl[i,:] @ W1[:CF])[h] * s[h]
// zt'[j,h] = ((ht[j,:] @ W1[CF:])[h] + b1[h] - rmean[h]) * s[h] + beta[h]
// s[h] = gamma[h] / sqrt(rvar[h] + 1e-4)
// Blocks: [0,576) row-GEMMs (8 rows each: 512 zl rows then 4096 zt rows),
//         576 = build wcomb[128][32], [577,633) atom_types, [633,657) bond_types
// ---------------------------------------------------------------------------
__global__ __launch_bounds__(256) void k_pre(
    const float* __restrict__ hl,
    const float* __restrict__ ht,
    const int*   __restrict__ eidx,
    const float* __restrict__ W1,
    const float* __restrict__ b1,
    const float* __restrict__ gamma_,
    const float* __restrict__ beta_,
    const float* __restrict__ rmean,
    const float* __restrict__ rvar,
    const float* __restrict__ Wpi,
    const float* __restrict__ Wsig,
    const float* __restrict__ Wmu,
    const float* __restrict__ Wat,
    const float* __restrict__ bat,
    const float* __restrict__ Wbd,
    const float* __restrict__ bbd,
    unsigned short* __restrict__ zl,
    unsigned short* __restrict__ zt,
    unsigned short* __restrict__ wcomb,
    float* __restrict__ out_at,
    float* __restrict__ out_bd)
{
    const int blk = blockIdx.x;
    const int tid = threadIdx.x;

    if (blk < 576) {
        __shared__ float xs[8 * CF];
        const int r0 = blk * 8;
        const bool is_l = (r0 < 512);
        const float* src = is_l ? (hl + (size_t)r0 * CF)
                                : (ht + (size_t)(r0 - 512) * CF);
        for (int i = tid; i < 8 * CF; i += 256) xs[i] = src[i];
        __syncthreads();

        const int h  = tid & 127;
        const int rr = (tid >> 7) * 4;   // rows rr..rr+3 of the 8
        float a0 = 0.f, a1 = 0.f, a2 = 0.f, a3 = 0.f;
        const float* wp = W1 + (size_t)(is_l ? 0 : CF) * HD + h;
        #pragma unroll 4
        for (int c = 0; c < CF; ++c) {
            float w = wp[(size_t)c * HD];
            a0 += xs[(rr + 0) * CF + c] * w;
            a1 += xs[(rr + 1) * CF + c] * w;
            a2 += xs[(rr + 2) * CF + c] * w;
            a3 += xs[(rr + 3) * CF + c] * w;
        }
        const float s = gamma_[h] * rsqrtf(rvar[h] + 1e-4f);
        if (is_l) {
            zl[(size_t)(r0 + rr + 0) * HD + h] = f2bf(a0 * s);
            zl[(size_t)(r0 + rr + 1) * HD + h] = f2bf(a1 * s);
            zl[(size_t)(r0 + rr + 2) * HD + h] = f2bf(a2 * s);
            zl[(size_t)(r0 + rr + 3) * HD + h] = f2bf(a3 * s);
        } else {
            const float off = (b1[h] - rmean[h]) * s + beta_[h];
            const int rt = r0 - 512 + rr;
            zt[(size_t)(rt + 0) * HD + h] = f2bf(a0 * s + off);
            zt[(size_t)(rt + 1) * HD + h] = f2bf(a1 * s + off);
            zt[(size_t)(rt + 2) * HD + h] = f2bf(a2 * s + off);
            zt[(size_t)(rt + 3) * HD + h] = f2bf(a3 * s + off);
        }
    } else if (blk == 576) {
        // wcomb[h][n]: n 0-9 = Wpi, 10-19 = Wsig, 20-29 = Wmu, 30-31 = 0
        for (int i = tid; i < HD * 32; i += 256) {
            int hh = i >> 5, n = i & 31;
            float v = 0.f;
            if (n < 10)      v = Wpi [hh * NK + n];
            else if (n < 20) v = Wsig[hh * NK + (n - 10)];
            else if (n < 30) v = Wmu [hh * NK + (n - 20)];
            wcomb[i] = f2bf(v);
        }
    } else if (blk < 633) {
        // atom_types: 512x28, one output per thread (56 blocks * 256 = 14336)
        const int oi = (blk - 577) * 256 + tid;
        const int r = oi / 28, n = oi - r * 28;
        float acc = bat[n];
        #pragma unroll 4
        for (int c = 0; c < CF; ++c)
            acc += hl[(size_t)r * CF + c] * Wat[c * 28 + n];
        out_at[oi] = acc;
    } else {
        // bond_types: 1024x6 (24 blocks * 256 = 6144)
        const int oi = (blk - 633) * 256 + tid;
        const int e = oi / 6, n = oi - e * 6;
        const int s0 = eidx[e], s1 = eidx[NE + e];
        float acc = bbd[n];
        #pragma unroll 4
        for (int c = 0; c < CF; ++c) {
            acc += hl[(size_t)s0 * CF + c] * Wbd[c * 6 + n];
            acc += hl[(size_t)s1 * CF + c] * Wbd[(CF + c) * 6 + n];
        }
        out_bd[oi] = acc;
    }
}

// ---------------------------------------------------------------------------
// Kernel 2: one block per (b,l). 4 chunks of 128 t's:
//   stage1: C[p][h] = ELU(zl'[h] + zt'[t][h])  -> LDS (row stride 136 shorts)
//   stage2: MFMA 16x16x32_bf16: [128 pairs x 128] @ [128 x 32]  -> Dl (stride 33)
//   stage3: softmax(pi)+bias / ELU(sigma)+1.1 / ELU(mu)+1.0 / dist / C_batch
// ---------------------------------------------------------------------------
__global__ __launch_bounds__(256) void k_main(
    const unsigned short* __restrict__ zl,
    const unsigned short* __restrict__ zt,
    const unsigned short* __restrict__ wcomb,
    const float* __restrict__ bpi,
    const float* __restrict__ bsig,
    const float* __restrict__ bmu,
    const float* __restrict__ hlpos,
    const float* __restrict__ htpos,
    float* __restrict__ out)
{
    __shared__ unsigned short Cl[128 * 136];  // 34816 B, +8 shorts/row pad
    __shared__ float Dl[128 * 33];            // 16896 B, +1 float/row pad
    __shared__ float zls[HD];
    __shared__ float biass[32];
    __shared__ float pls[4];

    const int tid  = threadIdx.x;
    const int blk  = blockIdx.x;
    const int b    = blk >> 6;
    const int l    = blk & 63;
    const int lane = tid & 63;
    const int wave = tid >> 6;

    if (tid < 128) {
        zls[tid] = bf2f(zl[(size_t)(b * NL + l) * HD + tid]);
    } else if (tid < 160) {
        int n = tid - 128;
        float v = 0.f;
        if (n < 10)      v = bpi[n];
        else if (n < 20) v = bsig[n - 10];
        else if (n < 30) v = bmu[n - 20];
        biass[n] = v;
    } else if (tid < 163) {
        pls[tid - 160] = hlpos[(size_t)(b * NL + l) * 3 + (tid - 160)];
    }

    // B fragments: B[k][n], n = lane&15 (+16 for tile 1), k = kb*32 + (lane>>4)*8 + j
    short8 bfrag[2][4];
    #pragma unroll
    for (int nt = 0; nt < 2; ++nt) {
        #pragma unroll
        for (int kb = 0; kb < 4; ++kb) {
            const int n = nt * 16 + (lane & 15);
            const int kbase = kb * 32 + (lane >> 4) * 8;
            #pragma unroll
            for (int j = 0; j < 8; ++j)
                bfrag[nt][kb][j] = (short)wcomb[(kbase + j) * 32 + n];
        }
    }
    __syncthreads();

    for (int ch = 0; ch < 4; ++ch) {
        const int tc = ch * 128;

        // ---- stage 1: elementwise C-tile ----
        {
            const int p  = tid >> 1;
            const int h0 = (tid & 1) * 64;
            const unsigned short* ztr = zt + (size_t)(b * NT + tc + p) * HD + h0;
            #pragma unroll
            for (int hh = 0; hh < 64; hh += 8) {
                short8 zv = *(const short8*)(ztr + hh);
                short8 cv;
                #pragma unroll
                for (int e2 = 0; e2 < 8; ++e2) {
                    float a = zls[h0 + hh + e2] + bf2f((unsigned short)zv[e2]);
                    float c = (a > 0.f) ? a : (__expf(a) - 1.f);
                    cv[e2] = (short)f2bf(c);
                }
                *(short8*)(&Cl[p * 136 + h0 + hh]) = cv;
            }
        }
        __syncthreads();

        // ---- stage 2: MFMA ----
        floatx4 acc[2][2];
        #pragma unroll
        for (int i = 0; i < 2; ++i)
            #pragma unroll
            for (int j = 0; j < 2; ++j)
                acc[i][j] = (floatx4){0.f, 0.f, 0.f, 0.f};

        const int m = lane & 15;
        #pragma unroll
        for (int kb = 0; kb < 4; ++kb) {
            const int ko = kb * 32 + (lane >> 4) * 8;
            short8 a0 = *(const short8*)(&Cl[(wave * 32 + m) * 136 + ko]);
            short8 a1 = *(const short8*)(&Cl[(wave * 32 + 16 + m) * 136 + ko]);
            #pragma unroll
            for (int nt = 0; nt < 2; ++nt) {
                acc[0][nt] = __builtin_amdgcn_mfma_f32_16x16x32_bf16(a0, bfrag[nt][kb], acc[0][nt], 0, 0, 0);
                acc[1][nt] = __builtin_amdgcn_mfma_f32_16x16x32_bf16(a1, bfrag[nt][kb], acc[1][nt], 0, 0, 0);
            }
        }
        // D: col = lane&15, row = (lane>>4)*4 + r   [verified m89/m91]
        #pragma unroll
        for (int pt = 0; pt < 2; ++pt)
            #pragma unroll
            for (int nt = 0; nt < 2; ++nt)
                #pragma unroll
                for (int r = 0; r < 4; ++r) {
                    const int row = wave * 32 + pt * 16 + (lane >> 4) * 4 + r;
                    const int col = nt * 16 + (lane & 15);
                    Dl[row * 33 + col] = acc[pt][nt][r];
                }
        __syncthreads();

        // ---- stage 3: epilogues (fp32 stores) ----
        const size_t gp = ((size_t)(b * NL + l)) * NT + tc + (tid & 127);
        if (tid < 128) {
            const int p = tid;
            float v[10];
            float mx = -1e30f;
            #pragma unroll
            for (int n = 0; n < 10; ++n) {
                v[n] = Dl[p * 33 + n] + biass[n];
                mx = fmaxf(mx, v[n]);
            }
            float s = 0.f;
            #pragma unroll
            for (int n = 0; n < 10; ++n) { v[n] = __expf(v[n] - mx); s += v[n]; }
            const float inv = 1.f / s;
            floatx2* po = (floatx2*)(out + PI_OFF + gp * 10);
            #pragma unroll
            for (int n = 0; n < 5; ++n) po[n] = (floatx2){v[2*n] * inv, v[2*n+1] * inv};
        } else {
            const int p = tid - 128;
            float sg[10], mv[10];
            #pragma unroll
            for (int n = 0; n < 10; ++n) {
                float x = Dl[p * 33 + 10 + n] + biass[10 + n];
                sg[n] = ((x > 0.f) ? x : (__expf(x) - 1.f)) + 1.1f;
                float y = Dl[p * 33 + 20 + n] + biass[20 + n];
                mv[n] = ((y > 0.f) ? y : (__expf(y) - 1.f)) + 1.0f;
            }
            floatx2* ps = (floatx2*)(out + SIG_OFF + gp * 10);
            floatx2* pm = (floatx2*)(out + MU_OFF  + gp * 10);
            #pragma unroll
            for (int n = 0; n < 5; ++n) {
                ps[n] = (floatx2){sg[2*n], sg[2*n+1]};
                pm[n] = (floatx2){mv[2*n], mv[2*n+1]};
            }
            const int t = tc + p;
            const size_t pb = (size_t)(b * NT + t) * 3;
            const float dx = pls[0] - htpos[pb + 0];
            const float dy = pls[1] - htpos[pb + 1];
            const float dz = pls[2] - htpos[pb + 2];
            out[DIST_OFF + gp] = sqrtf(dx * dx + dy * dy + dz * dz);
            out[CB_OFF + gp]   = (float)b;
        }
        __syncthreads();
    }
}

// ---------------------------------------------------------------------------
extern "C" void kernel_launch(void* const* d_in, const int* in_sizes, int n_in,
                              void* d_out, int out_size, void* d_ws, size_t ws_size,
                              hipStream_t stream)
{
    const float* hl     = (const float*)d_in[0];
    const float* ht     = (const float*)d_in[1];
    const float* hlpos  = (const float*)d_in[2];
    const float* htpos  = (const float*)d_in[3];
    const int*   eidx   = (const int*)d_in[4];
    const float* W1     = (const float*)d_in[5];
    const float* b1     = (const float*)d_in[6];
    const float* gamma_ = (const float*)d_in[7];
    const float* beta_  = (const float*)d_in[8];
    const float* rmean  = (const float*)d_in[9];
    const float* rvar   = (const float*)d_in[10];
    const float* Wpi    = (const float*)d_in[11];
    const float* bpi    = (const float*)d_in[12];
    const float* Wsig   = (const float*)d_in[13];
    const float* bsig   = (const float*)d_in[14];
    const float* Wmu    = (const float*)d_in[15];
    const float* bmu    = (const float*)d_in[16];
    const float* Wat    = (const float*)d_in[17];
    const float* bat    = (const float*)d_in[18];
    const float* Wbd    = (const float*)d_in[19];
    const float* bbd    = (const float*)d_in[20];

    float* out = (float*)d_out;
    unsigned short* ws  = (unsigned short*)d_ws;
    unsigned short* zl    = ws;                          // 512*128 bf16
    unsigned short* zt    = ws + 512 * 128;              // 4096*128 bf16
    unsigned short* wcomb = ws + 512 * 128 + 4096 * 128; // 128*32 bf16

    k_pre<<<657, 256, 0, stream>>>(hl, ht, eidx, W1, b1, gamma_, beta_, rmean, rvar,
                                   Wpi, Wsig, Wmu, Wat, bat, Wbd, bbd,
                                   zl, zt, wcomb, out + AT_OFF, out + BD_OFF);
    k_main<<<512, 256, 0, stream>>>(zl, zt, wcomb, bpi, bsig, bmu, hlpos, htpos, out);
}

// Round 4
// 137.363 us; speedup vs baseline: 1.0162x; 1.0162x over previous
//
#include <hip/hip_runtime.h>
#include <cstdint>
#include <cstddef>

// Problem constants
#define NB_B 8
#define NL   64
#define NT   512
#define CF   128
#define HD   128
#define NK   10
#define NE   1024

// d_out flat offsets (fp32 elements), reference return order:
// pi[P,10], sigma[P,10], mu[P,10], dist[P,1], atom_types[512,28], bond_types[1024,6], C_batch[P]
static constexpr size_t P_TOT    = (size_t)NB_B * NL * NT;     // 262144
static constexpr size_t PI_OFF   = 0;
static constexpr size_t SIG_OFF  = P_TOT * 10;                  // 2621440
static constexpr size_t MU_OFF   = SIG_OFF + P_TOT * 10;        // 5242880
static constexpr size_t DIST_OFF = MU_OFF + P_TOT * 10;         // 7864320
static constexpr size_t AT_OFF   = DIST_OFF + P_TOT;            // 8126464
static constexpr size_t BD_OFF   = AT_OFF + 512 * 28;           // 8140800
static constexpr size_t CB_OFF   = BD_OFF + NE * 6;             // 8146944

typedef __attribute__((ext_vector_type(8))) short short8;
typedef __attribute__((ext_vector_type(4))) float floatx4;
typedef __attribute__((ext_vector_type(2))) float floatx2;

__device__ __forceinline__ float bf2f(unsigned short u) {
    return __uint_as_float(((unsigned int)u) << 16);
}
__device__ __forceinline__ unsigned short f2bf(float f) {
    unsigned int x = __float_as_uint(f);
    x = (x + 0x7FFFu + ((x >> 16) & 1u)) >> 16;   // RNE
    return (unsigned short)x;
}

// ---------------------------------------------------------------------------
// Kernel 1: blocks [0,144) = MFMA GEMM producing zl' (16 blocks) / zt' (128
// blocks), 32 rows each; block 144 = wcomb_t; [145,201) atom_types;
// [201,225) bond_types.
//   zl'[i,h] = (hl[i,:] @ W1[:CF])[h] * s[h]
//   zt'[j,h] = ((ht[j,:] @ W1[CF:])[h]) * s[h] + off[h],
//   s[h] = gamma/sqrt(rvar+1e-4), off[h] = (b1-rmean)*s + beta
// MFMA frag conventions (validated R3): A[m=lane&15][k=(lane>>4)*8+j],
// B[k][n=lane&15], D col=lane&15, row=(lane>>4)*4+r.
// ---------------------------------------------------------------------------
__global__ __launch_bounds__(256) void k_pre(
    const float* __restrict__ hl,
    const float* __restrict__ ht,
    const int*   __restrict__ eidx,
    const float* __restrict__ W1,
    const float* __restrict__ b1,
    const float* __restrict__ gamma_,
    const float* __restrict__ beta_,
    const float* __restrict__ rmean,
    const float* __restrict__ rvar,
    const float* __restrict__ Wpi,
    const float* __restrict__ Wsig,
    const float* __restrict__ Wmu,
    const float* __restrict__ Wat,
    const float* __restrict__ bat,
    const float* __restrict__ Wbd,
    const float* __restrict__ bbd,
    unsigned short* __restrict__ zl,
    unsigned short* __restrict__ zt,
    unsigned short* __restrict__ wcomb_t,
    float* __restrict__ out_at,
    float* __restrict__ out_bd)
{
    const int blk = blockIdx.x;
    const int tid = threadIdx.x;

    if (blk < 144) {
        const bool is_l = (blk < 16);
        const int rbase = is_l ? blk * 32 : (blk - 16) * 32;
        const float* A  = is_l ? hl : ht;
        const float* Wx = W1 + (is_l ? 0 : (size_t)CF * HD);   // [128 c][128 h]
        unsigned short* Z = is_l ? zl : zt;

        const int wave = tid >> 6;
        const int lane = tid & 63;
        const int m    = lane & 15;
        const int kq   = (lane >> 4) * 8;
        const int n0   = wave * 32 + m;          // col for nt=0 (+16 for nt=1)

        floatx4 acc[2][2];
        #pragma unroll
        for (int i = 0; i < 2; ++i)
            #pragma unroll
            for (int j = 0; j < 2; ++j)
                acc[i][j] = (floatx4){0.f, 0.f, 0.f, 0.f};

        #pragma unroll
        for (int kb = 0; kb < 4; ++kb) {
            const int k0 = kb * 32 + kq;
            short8 a[2];
            #pragma unroll
            for (int mt = 0; mt < 2; ++mt) {
                const float* ap = A + (size_t)(rbase + mt * 16 + m) * CF + k0;
                floatx4 f0 = *(const floatx4*)ap;
                floatx4 f1 = *(const floatx4*)(ap + 4);
                #pragma unroll
                for (int j = 0; j < 4; ++j) {
                    a[mt][j]     = (short)f2bf(f0[j]);
                    a[mt][4 + j] = (short)f2bf(f1[j]);
                }
            }
            short8 bf[2];
            #pragma unroll
            for (int nt = 0; nt < 2; ++nt) {
                const int n = n0 + nt * 16;
                #pragma unroll
                for (int j = 0; j < 8; ++j)
                    bf[nt][j] = (short)f2bf(Wx[(size_t)(k0 + j) * HD + n]);
            }
            #pragma unroll
            for (int mt = 0; mt < 2; ++mt)
                #pragma unroll
                for (int nt = 0; nt < 2; ++nt)
                    acc[mt][nt] = __builtin_amdgcn_mfma_f32_16x16x32_bf16(a[mt], bf[nt], acc[mt][nt], 0, 0, 0);
        }

        #pragma unroll
        for (int nt = 0; nt < 2; ++nt) {
            const int col = n0 + nt * 16;
            const float s   = gamma_[col] * rsqrtf(rvar[col] + 1e-4f);
            const float off = is_l ? 0.f : ((b1[col] - rmean[col]) * s + beta_[col]);
            #pragma unroll
            for (int mt = 0; mt < 2; ++mt)
                #pragma unroll
                for (int r = 0; r < 4; ++r) {
                    const int row = rbase + mt * 16 + (lane >> 4) * 4 + r;
                    Z[(size_t)row * HD + col] = f2bf(acc[mt][nt][r] * s + off);
                }
        }
    } else if (blk == 144) {
        // wcomb_t[n][k]: n 0-9 = Wpi col, 10-19 = Wsig, 20-29 = Wmu, 30-31 = 0
        for (int i = tid; i < 32 * HD; i += 256) {
            const int n = i >> 7, k = i & 127;
            float v = 0.f;
            if (n < 10)      v = Wpi [k * NK + n];
            else if (n < 20) v = Wsig[k * NK + (n - 10)];
            else if (n < 30) v = Wmu [k * NK + (n - 20)];
            wcomb_t[i] = f2bf(v);
        }
    } else if (blk < 201) {
        // atom_types: 512x28 (56 blocks * 256 = 14336)
        const int oi = (blk - 145) * 256 + tid;
        const int r = oi / 28, n = oi - r * 28;
        float acc = bat[n];
        #pragma unroll 4
        for (int c = 0; c < CF; ++c)
            acc += hl[(size_t)r * CF + c] * Wat[c * 28 + n];
        out_at[oi] = acc;
    } else {
        // bond_types: 1024x6 (24 blocks * 256 = 6144)
        const int oi = (blk - 201) * 256 + tid;
        const int e = oi / 6, n = oi - e * 6;
        const int s0 = eidx[e], s1 = eidx[NE + e];
        float acc = bbd[n];
        #pragma unroll 4
        for (int c = 0; c < CF; ++c) {
            acc += hl[(size_t)s0 * CF + c] * Wbd[c * 6 + n];
            acc += hl[(size_t)s1 * CF + c] * Wbd[(CF + c) * 6 + n];
        }
        out_bd[oi] = acc;
    }
}

// ---------------------------------------------------------------------------
// Kernel 2: one block per (b, l, chunk-of-128-t): 2048 blocks, 256 threads.
// Each lane computes its MFMA A-fragments (ELU(zl'+zt')) DIRECTLY from
// global zl/zt (L2-resident) — no C staging in LDS, 2 barriers total.
//   stage A: per-lane ELU + 16 MFMAs  ->  Dl[128][33] (f32, padded)
//   stage B: softmax(pi)/ELU(sigma)+1.1/ELU(mu)+1.0/dist/C_batch, fp32 out
// ---------------------------------------------------------------------------
__global__ __launch_bounds__(256) void k_main(
    const unsigned short* __restrict__ zl,
    const unsigned short* __restrict__ zt,
    const unsigned short* __restrict__ wcomb_t,
    const float* __restrict__ bpi,
    const float* __restrict__ bsig,
    const float* __restrict__ bmu,
    const float* __restrict__ hlpos,
    const float* __restrict__ htpos,
    float* __restrict__ out)
{
    __shared__ float Dl[128 * 33];   // 16.9 KB
    __shared__ float biass[32];
    __shared__ float pls[3];

    const int tid  = threadIdx.x;
    const int blk  = blockIdx.x;
    const int b    = blk >> 8;
    const int l    = (blk >> 2) & 63;
    const int ch   = blk & 3;
    const int lane = tid & 63;
    const int wave = tid >> 6;
    const int m    = lane & 15;
    const int kq   = (lane >> 4) * 8;

    if (tid < 32) {
        float v = 0.f;
        if (tid < 10)      v = bpi[tid];
        else if (tid < 20) v = bsig[tid - 10];
        else if (tid < 30) v = bmu[tid - 20];
        biass[tid] = v;
    } else if (tid < 35) {
        pls[tid - 32] = hlpos[(size_t)(b * NL + l) * 3 + (tid - 32)];
    }

    // B fragments: single 16B loads from transposed head weights
    short8 bfrag[2][4];
    #pragma unroll
    for (int nt = 0; nt < 2; ++nt)
        #pragma unroll
        for (int kb = 0; kb < 4; ++kb)
            bfrag[nt][kb] = *(const short8*)(wcomb_t + (size_t)(nt * 16 + m) * HD + kb * 32 + kq);

    // ---- stage A: direct A-frag compute + MFMA ----
    const unsigned short* zlr = zl + (size_t)(b * NL + l) * HD;
    const unsigned short* ztb = zt + (size_t)(b * NT + ch * 128) * HD;

    floatx4 acc[2][2];
    #pragma unroll
    for (int i = 0; i < 2; ++i)
        #pragma unroll
        for (int j = 0; j < 2; ++j)
            acc[i][j] = (floatx4){0.f, 0.f, 0.f, 0.f};

    #pragma unroll
    for (int kb = 0; kb < 4; ++kb) {
        const int k0 = kb * 32 + kq;
        short8 zlv = *(const short8*)(zlr + k0);
        float zf[8];
        #pragma unroll
        for (int j = 0; j < 8; ++j) zf[j] = bf2f((unsigned short)zlv[j]);

        short8 a[2];
        #pragma unroll
        for (int mt = 0; mt < 2; ++mt) {
            const int row = wave * 32 + mt * 16 + m;
            short8 ztv = *(const short8*)(ztb + (size_t)row * HD + k0);
            #pragma unroll
            for (int j = 0; j < 8; ++j) {
                const float x = zf[j] + bf2f((unsigned short)ztv[j]);
                const float c = (x > 0.f) ? x : (__expf(x) - 1.f);
                a[mt][j] = (short)f2bf(c);
            }
        }
        #pragma unroll
        for (int mt = 0; mt < 2; ++mt)
            #pragma unroll
            for (int nt = 0; nt < 2; ++nt)
                acc[mt][nt] = __builtin_amdgcn_mfma_f32_16x16x32_bf16(a[mt], bfrag[nt][kb], acc[mt][nt], 0, 0, 0);
    }

    // D: col = lane&15, row = (lane>>4)*4 + r   [validated R3]
    #pragma unroll
    for (int mt = 0; mt < 2; ++mt)
        #pragma unroll
        for (int nt = 0; nt < 2; ++nt)
            #pragma unroll
            for (int r = 0; r < 4; ++r) {
                const int row = wave * 32 + mt * 16 + (lane >> 4) * 4 + r;
                const int col = nt * 16 + m;
                Dl[row * 33 + col] = acc[mt][nt][r];
            }
    __syncthreads();

    // ---- stage B: epilogues (fp32 stores) ----
    const size_t gp = ((size_t)(b * NL + l)) * NT + ch * 128 + (tid & 127);
    if (tid < 128) {
        const int p = tid;
        float v[10];
        float mx = -1e30f;
        #pragma unroll
        for (int n = 0; n < 10; ++n) {
            v[n] = Dl[p * 33 + n] + biass[n];
            mx = fmaxf(mx, v[n]);
        }
        float s = 0.f;
        #pragma unroll
        for (int n = 0; n < 10; ++n) { v[n] = __expf(v[n] - mx); s += v[n]; }
        const float inv = 1.f / s;
        floatx2* po = (floatx2*)(out + PI_OFF + gp * 10);
        #pragma unroll
        for (int n = 0; n < 5; ++n) po[n] = (floatx2){v[2*n] * inv, v[2*n+1] * inv};
    } else {
        const int p = tid - 128;
        float sg[10], mv[10];
        #pragma unroll
        for (int n = 0; n < 10; ++n) {
            const float x = Dl[p * 33 + 10 + n] + biass[10 + n];
            sg[n] = ((x > 0.f) ? x : (__expf(x) - 1.f)) + 1.1f;
            const float y = Dl[p * 33 + 20 + n] + biass[20 + n];
            mv[n] = ((y > 0.f) ? y : (__expf(y) - 1.f)) + 1.0f;
        }
        floatx2* ps = (floatx2*)(out + SIG_OFF + gp * 10);
        floatx2* pm = (floatx2*)(out + MU_OFF  + gp * 10);
        #pragma unroll
        for (int n = 0; n < 5; ++n) {
            ps[n] = (floatx2){sg[2*n], sg[2*n+1]};
            pm[n] = (floatx2){mv[2*n], mv[2*n+1]};
        }
        const int t = ch * 128 + p;
        const size_t pb = (size_t)(b * NT + t) * 3;
        const float dx = pls[0] - htpos[pb + 0];
        const float dy = pls[1] - htpos[pb + 1];
        const float dz = pls[2] - htpos[pb + 2];
        out[DIST_OFF + gp] = sqrtf(dx * dx + dy * dy + dz * dz);
        out[CB_OFF + gp]   = (float)b;
    }
}

// ---------------------------------------------------------------------------
extern "C" void kernel_launch(void* const* d_in, const int* in_sizes, int n_in,
                              void* d_out, int out_size, void* d_ws, size_t ws_size,
                              hipStream_t stream)
{
    const float* hl     = (const float*)d_in[0];
    const float* ht     = (const float*)d_in[1];
    const float* hlpos  = (const float*)d_in[2];
    const float* htpos  = (const float*)d_in[3];
    const int*   eidx   = (const int*)d_in[4];
    const float* W1     = (const float*)d_in[5];
    const float* b1     = (const float*)d_in[6];
    const float* gamma_ = (const float*)d_in[7];
    const float* beta_  = (const float*)d_in[8];
    const float* rmean  = (const float*)d_in[9];
    const float* rvar   = (const float*)d_in[10];
    const float* Wpi    = (const float*)d_in[11];
    const float* bpi    = (const float*)d_in[12];
    const float* Wsig   = (const float*)d_in[13];
    const float* bsig   = (const float*)d_in[14];
    const float* Wmu    = (const float*)d_in[15];
    const float* bmu    = (const float*)d_in[16];
    const float* Wat    = (const float*)d_in[17];
    const float* bat    = (const float*)d_in[18];
    const float* Wbd    = (const float*)d_in[19];
    const float* bbd    = (const float*)d_in[20];

    float* out = (float*)d_out;
    unsigned short* ws  = (unsigned short*)d_ws;
    unsigned short* zl      = ws;                          // 512*128 bf16
    unsigned short* zt      = ws + 512 * 128;              // 4096*128 bf16
    unsigned short* wcomb_t = ws + 512 * 128 + 4096 * 128; // 32*128 bf16

    k_pre<<<225, 256, 0, stream>>>(hl, ht, eidx, W1, b1, gamma_, beta_, rmean, rvar,
                                   Wpi, Wsig, Wmu, Wat, bat, Wbd, bbd,
                                   zl, zt, wcomb_t, out + AT_OFF, out + BD_OFF);
    k_main<<<2048, 256, 0, stream>>>(zl, zt, wcomb_t, bpi, bsig, bmu, hlpos, htpos, out);
}